// Round 14
// baseline (79.284 us; speedup 1.0000x reference)
//
#include <hip/hip_runtime.h>
#include <stdint.h>

typedef float f32x4 __attribute__((ext_vector_type(4)));
typedef unsigned long long u64;

#define HEADS 12
#define DDIM 64
#define LSEQ 512
#define HID 768
#define NOUT 1536
#define BIG_NEG 1000000000000.0f

__device__ __forceinline__ void gl_lds16(const void* g, void* l) {
    __builtin_amdgcn_global_load_lds(
        (const __attribute__((address_space(1))) void*)g,
        (__attribute__((address_space(3))) void*)l, 16, 0, 0);
}

// barrier that orders LDS only — does NOT drain vmcnt
__device__ __forceinline__ void ldsbar() {
    asm volatile("s_waitcnt lgkmcnt(0)" ::: "memory");
    __builtin_amdgcn_s_barrier();
}

__device__ __forceinline__ uint32_t pk4_fp8(float a, float b, float c, float d) {
    uint32_t v = __builtin_amdgcn_cvt_pk_fp8_f32(a, b, 0, false);
    v = __builtin_amdgcn_cvt_pk_fp8_f32(c, d, v, true);
    return v;
}

// ---- kernel 1 (fused prep): X->fp8, W->Wt fp8 transpose, RoPE tables --------
__global__ __launch_bounds__(256) void prep_k(
    const float* __restrict__ X, const float* __restrict__ W,
    uint8_t* __restrict__ Xq, uint8_t* __restrict__ Wtq,
    float* __restrict__ cosT, float* __restrict__ sinT) {

    int blk = blockIdx.x;
    if (blk < 3072) {
        size_t idx = ((size_t)blk * 256 + threadIdx.x) * 8;
        float4 f0 = *(const float4*)(X + idx);
        float4 f1 = *(const float4*)(X + idx + 4);
        uint2 p;
        p.x = pk4_fp8(f0.x, f0.y, f0.z, f0.w);
        p.y = pk4_fp8(f1.x, f1.y, f1.z, f1.w);
        *(uint2*)(Xq + idx) = p;
    } else if (blk < 4224) {
        __shared__ float Ls[32][33];
        int b2 = blk - 3072;
        int n0 = (b2 % 48) * 32, k0 = (b2 / 48) * 32;
        int tx = threadIdx.x & 31, ty = threadIdx.x >> 5;
#pragma unroll
        for (int rr = 0; rr < 4; ++rr) {
            int k = ty + rr * 8;
            Ls[k][tx] = W[(size_t)(k0 + k) * NOUT + n0 + tx];
        }
        __syncthreads();
        int n = threadIdx.x >> 3, c = threadIdx.x & 7;
        uint32_t w = pk4_fp8(Ls[4*c][n], Ls[4*c+1][n], Ls[4*c+2][n], Ls[4*c+3][n]);
        *(uint32_t*)(Wtq + (size_t)(n0 + n) * HID + k0 + c * 4) = w;
    } else {
        int idx = (blk - 4224) * 256 + threadIdx.x;
        int l = idx >> 6, d = idx & 63;
        int p = d >> 1;
        float inv = powf(10000.0f, (-2.0f * (float)p) / 64.0f);
        float ang = (float)l * inv;
        cosT[idx] = cosf(ang);
        sinT[idx] = sinf(ang);
    }
}

// ---------------- kernel 2: fp8 proj GEMM + bias + RoPE -> fp8 q/k slabs -----
// (round-11 winner: double-buffered LDS + prefetch + counted vmcnt(4))
__global__ __launch_bounds__(256) void proj_rope_k(
    const uint8_t* __restrict__ Xq, const uint8_t* __restrict__ Wtq,
    const float* __restrict__ bias, const float* __restrict__ cosT,
    const float* __restrict__ sinT,
    uint8_t* __restrict__ qq, uint8_t* __restrict__ kq) {

    __shared__ __align__(16) uint8_t As[2][128 * 64];
    __shared__ __align__(16) uint8_t Bs[2][128 * 64];

    const int tid = threadIdx.x;
    const int m0 = blockIdx.x * 128, n0 = blockIdx.y * 128;
    const int lane = tid & 63, wid = tid >> 6;
    const int wm = wid >> 1, wn = wid & 1;
    const int lr = lane & 15, kg = lane >> 4;

    const int srow = tid >> 2, sc = tid & 3;

    f32x4 acc[4][4] = {};                 // [ai(n)][bi(m)]

    // prologue: stage tile 0 -> buf 0
#pragma unroll
    for (int j = 0; j < 2; ++j) {
        int r = j * 64 + srow;
        int cs = sc ^ ((r >> 1) & 3);
        gl_lds16(Wtq + (size_t)(n0 + r) * HID + cs * 16, Bs[0] + j * 4096 + tid * 16);
        gl_lds16(Xq  + (size_t)(m0 + r) * HID + cs * 16, As[0] + j * 4096 + tid * 16);
    }

    for (int it = 0; it < 12; ++it) {
        const int cur = it & 1;
        if (it < 11) {
            const int k0 = (it + 1) * 64;
            // prefetch tile it+1 into the other buffer
#pragma unroll
            for (int j = 0; j < 2; ++j) {
                int r = j * 64 + srow;
                int cs = sc ^ ((r >> 1) & 3);
                gl_lds16(Wtq + (size_t)(n0 + r) * HID + k0 + cs * 16,
                         Bs[cur ^ 1] + j * 4096 + tid * 16);
                gl_lds16(Xq  + (size_t)(m0 + r) * HID + k0 + cs * 16,
                         As[cur ^ 1] + j * 4096 + tid * 16);
            }
            // retire tile it's 4 loads; tile it+1's 4 float through
            asm volatile("s_waitcnt vmcnt(4)" ::: "memory");
        } else {
            asm volatile("s_waitcnt vmcnt(0)" ::: "memory");
        }
        __builtin_amdgcn_s_barrier();

#pragma unroll
        for (int ks = 0; ks < 2; ++ks) {
            u64 af[4], xf[4];
#pragma unroll
            for (int ai = 0; ai < 4; ++ai) {
                int row = wn * 64 + ai * 16 + lr;
                int sl = (ks * 4 + kg) ^ (row & 6);
                af[ai] = *(const u64*)(Bs[cur] + row * 64 + sl * 8);
            }
#pragma unroll
            for (int bi = 0; bi < 4; ++bi) {
                int row = wm * 64 + bi * 16 + lr;
                int sl = (ks * 4 + kg) ^ (row & 6);
                xf[bi] = *(const u64*)(As[cur] + row * 64 + sl * 8);
            }
#pragma unroll
            for (int ai = 0; ai < 4; ++ai)
#pragma unroll
                for (int bi = 0; bi < 4; ++bi)
                    acc[ai][bi] = __builtin_amdgcn_mfma_f32_16x16x32_fp8_fp8(
                        (long long)af[ai], (long long)xf[bi], acc[ai][bi], 0, 0, 0);
        }
        // all waves' ds_reads of buf[cur] done before iter it+1 overwrites it
        ldsbar();
    }

    // ---- epilogue: bias + in-lane RoPE, pack fp8, 4B stores ----
#pragma unroll
    for (int ai = 0; ai < 4; ++ai) {
        int nb = n0 + wn * 64 + ai * 16 + kg * 4;  // 4-aligned
        int h = nb >> 7, d2 = nb & 127;
        int d = d2 & 63;
        uint8_t* dst = (d2 >= 64) ? kq : qq;
        float4 b4 = *(const float4*)&bias[nb];
#pragma unroll
        for (int bi = 0; bi < 4; ++bi) {
            int m = m0 + wm * 64 + bi * 16 + lr;
            int bidx = m >> 9, lpos = m & 511;
            float4 c4 = *(const float4*)&cosT[lpos * 64 + d];
            float4 s4 = *(const float4*)&sinT[lpos * 64 + d];
            float v0 = acc[ai][bi][0] + b4.x;
            float v1 = acc[ai][bi][1] + b4.y;
            float v2 = acc[ai][bi][2] + b4.z;
            float v3 = acc[ai][bi][3] + b4.w;
            float o0 = v0 * c4.x - v1 * s4.x;
            float o1 = v1 * c4.y + v0 * s4.y;
            float o2 = v2 * c4.z - v3 * s4.z;
            float o3 = v3 * c4.w + v2 * s4.w;
            uint32_t pw = pk4_fp8(o0, o1, o2, o3);
            *(uint32_t*)(dst + (((size_t)bidx * HEADS + h) * LSEQ + lpos) * DDIM + d) = pw;
        }
    }
}

// ---------------- kernel 3: fp8 QK^T + mask/tril/scale, 128m x 512n ----------
// Round-12 structure; SINGLE change: causal-work-balanced block mapping.
// Within each XCD chunk of 96, blocks co-resident on a CU (stride-32 in issue
// order) now get CONSECUTIVE mtiles {t,t+1,t+2} instead of 3x the same mtile
// (worst-CU tile-work 12 -> 9 units). Bijective: i=(bid>>3); r=i&31, c=i>>5;
// bh_local=(r>>2)*3+c; mtile=(r+c)&3.
__global__ __launch_bounds__(256) void attn_k(
    const uint8_t* __restrict__ qq, const uint8_t* __restrict__ kq,
    const float* __restrict__ mask, float* __restrict__ out) {

    __shared__ __align__(16) uint8_t Ks[8192];
    __shared__ __align__(16) float Es[32 * 132];
    __shared__ int wok[4];

    const int tid = threadIdx.x;
    // XCD-chunked + causal-balanced mapping
    const int bid = blockIdx.x;
    const int i = bid >> 3;                 // 0..95 within XCD chunk
    const int r = i & 31, c = i >> 5;       // c in {0,1,2}
    const int bh = (bid & 7) * 24 + (r >> 2) * 3 + c;
    const int mtile = (r + c) & 3;
    const int m0 = mtile * 128;
    const int lane = tid & 63, wid = tid >> 6;
    const int wm = wid >> 1, wn = wid & 1;
    const int lr = lane & 15, kg = lane >> 4;
    const int b = bh / HEADS;

    // ---- fast-path gate: all pads over the skipped cols must be exactly 1 ----
    int myok = 1;
    for (int c0 = tid; c0 < m0; c0 += 256)
        myok &= (mask[b * LSEQ + c0] == 1.0f) ? 1 : 0;
    unsigned long long bal = __ballot(myok);
    if (lane == 0) wok[wid] = (bal == ~0ull) ? 1 : 0;
    ldsbar();
    const int nstart = (wok[0] & wok[1] & wok[2] & wok[3]) ? mtile : 0;

    const uint8_t* qbase = qq + ((size_t)bh * LSEQ + m0) * DDIM;
    const uint8_t* kbase = kq + (size_t)bh * LSEQ * DDIM;

    // stage K[nstart] (issue first so the DMA starts before the q loads)
    const int srow = tid >> 2, sc = tid & 3;
#pragma unroll
    for (int j = 0; j < 2; ++j) {
        int rr = j * 64 + srow;
        int cs = sc ^ ((rr >> 1) & 3);
        gl_lds16(kbase + (size_t)(nstart * 128 + rr) * DDIM + cs * 16,
                 Ks + j * 4096 + tid * 16);
    }

    // Q fragments straight to registers in true k-order (swizzle self-cancels):
    u64 qf[2][4];
#pragma unroll
    for (int ks = 0; ks < 2; ++ks)
#pragma unroll
        for (int bi = 0; bi < 4; ++bi)
            qf[ks][bi] = *(const u64*)(qbase + (size_t)(wm * 64 + bi * 16 + lr) * DDIM
                                       + (ks * 4 + kg) * 8);

    __syncthreads();   // full drain: K[nstart] resident (qf loads also done)

    const int colb = (tid & 31) * 4;            // 0..124
    const int rrow = tid >> 5;                  // 0..7
    float* obase = out + (size_t)bh * LSEQ * LSEQ;

    for (int nt = nstart; nt < 4; ++nt) {
        f32x4 acc[4][4] = {};                   // [ai(n)][bi(m)]
#pragma unroll
        for (int ks = 0; ks < 2; ++ks) {
            u64 af[4];
#pragma unroll
            for (int ai = 0; ai < 4; ++ai) {
                int row = wn * 64 + ai * 16 + lr;
                int sl = (ks * 4 + kg) ^ (row & 6);
                af[ai] = *(const u64*)(Ks + row * 64 + sl * 8);
            }
#pragma unroll
            for (int ai = 0; ai < 4; ++ai)
#pragma unroll
                for (int bi = 0; bi < 4; ++bi)
                    acc[ai][bi] = __builtin_amdgcn_mfma_f32_16x16x32_fp8_fp8(
                        (long long)af[ai], (long long)qf[ks][bi], acc[ai][bi], 0, 0, 0);
        }
        ldsbar();   // all waves' Ks reads complete -> safe to overwrite Ks

        const int n0 = nt * 128;
        const float4 p4 = *(const float4*)&mask[b * LSEQ + n0 + colb];

        if (nt < 3) {   // prefetch next K tile (streams under the epilogue)
#pragma unroll
            for (int j = 0; j < 2; ++j) {
                int rr = j * 64 + srow;
                int cs = sc ^ ((rr >> 1) & 3);
                gl_lds16(kbase + (size_t)((nt + 1) * 128 + rr) * DDIM + cs * 16,
                         Ks + j * 4096 + tid * 16);
            }
        }

        // ---- epilogue: 4 rounds of 32-row LDS transpose -> coalesced stores ----
#pragma unroll
        for (int p = 0; p < 4; ++p) {
            ldsbar();   // Es free of prior-round readers
            if (wm == (p >> 1)) {
                const int bi0 = (p & 1) * 2;
#pragma unroll
                for (int bb = 0; bb < 2; ++bb) {
                    int bi = bi0 + bb;
                    int row = bb * 16 + lr;                // 0..31
#pragma unroll
                    for (int ai = 0; ai < 4; ++ai) {
                        int n = wn * 64 + ai * 16 + kg * 4;
                        *(f32x4*)&Es[row * 132 + n] = acc[ai][bi];
                    }
                }
            }
            ldsbar();   // writes visible
#pragma unroll
            for (int j = 0; j < 4; ++j) {
                int rloc = rrow + j * 8;                   // 0..31
                int m = m0 + p * 32 + rloc;
                f32x4 v = *(f32x4*)&Es[rloc * 132 + colb];
                int n = n0 + colb;
                f32x4 o;
                o[0] = (v[0] * p4.x - (1.0f - p4.x) * BIG_NEG
                        - ((m > n + 0) ? BIG_NEG : 0.0f)) * 0.125f;
                o[1] = (v[1] * p4.y - (1.0f - p4.y) * BIG_NEG
                        - ((m > n + 1) ? BIG_NEG : 0.0f)) * 0.125f;
                o[2] = (v[2] * p4.z - (1.0f - p4.z) * BIG_NEG
                        - ((m > n + 2) ? BIG_NEG : 0.0f)) * 0.125f;
                o[3] = (v[3] * p4.w - (1.0f - p4.w) * BIG_NEG
                        - ((m > n + 3) ? BIG_NEG : 0.0f)) * 0.125f;
                __builtin_nontemporal_store(o, (f32x4*)&obase[(size_t)m * LSEQ + n]);
            }
        }

        if (nt < 3) {
            // collect prefetch: 16 newest (this phase's NT stores) may float,
            // everything older (incl. the 2 gl_lds) must be done.
            asm volatile("s_waitcnt vmcnt(16) lgkmcnt(0)" ::: "memory");
            __builtin_amdgcn_s_barrier();
        }
    }

    // ---- fast-fill: constant region (pad==1, m>n for whole tile) ----
    const float CONSTV = (-BIG_NEG) * 0.125f;   // bit-exact vs ref chain
    f32x4 cv = {CONSTV, CONSTV, CONSTV, CONSTV};
    for (int nt2 = 0; nt2 < nstart; ++nt2) {
        int n = nt2 * 128 + colb;
#pragma unroll
        for (int p = 0; p < 4; ++p)
#pragma unroll
            for (int j = 0; j < 4; ++j) {
                int m = m0 + p * 32 + rrow + j * 8;
                __builtin_nontemporal_store(cv, (f32x4*)&obase[(size_t)m * LSEQ + n]);
            }
    }
}

extern "C" void kernel_launch(void* const* d_in, const int* in_sizes, int n_in,
                              void* d_out, int out_size, void* d_ws, size_t ws_size,
                              hipStream_t stream) {
    const float* X    = (const float*)d_in[0];   // (16,512,768)
    const float* mask = (const float*)d_in[1];   // (16,512)
    const float* W    = (const float*)d_in[2];   // (768,1536)
    const float* bias = (const float*)d_in[3];   // (1536,)
    float* out = (float*)d_out;                  // (16,12,512,512)

    char* ws = (char*)d_ws;
    float*   cosT = (float*)ws;                      // 131072 B
    float*   sinT = (float*)(ws + 131072);           // 131072 B
    uint8_t* Wtq  = (uint8_t*)(ws + 262144);         // 1179648 B
    uint8_t* Xq   = (uint8_t*)(ws + 1441792);        // 6291456 B
    uint8_t* qq   = (uint8_t*)(ws + 7733248);        // 6291456 B
    uint8_t* kq   = (uint8_t*)(ws + 14024704);       // 6291456 B

    prep_k<<<4352, 256, 0, stream>>>(X, W, Xq, Wtq, cosT, sinT);
    proj_rope_k<<<dim3(64, 12), 256, 0, stream>>>(Xq, Wtq, bias, cosT, sinT, qq, kq);
    attn_k<<<768, 256, 0, stream>>>(qq, kq, mask, out);
}

// Round 15
// 75.330 us; speedup vs baseline: 1.0525x; 1.0525x over previous
//
#include <hip/hip_runtime.h>
#include <stdint.h>

typedef float f32x4 __attribute__((ext_vector_type(4)));
typedef unsigned long long u64;

#define HEADS 12
#define DDIM 64
#define LSEQ 512
#define HID 768
#define NOUT 1536
#define BIG_NEG 1000000000000.0f

__device__ __forceinline__ void gl_lds16(const void* g, void* l) {
    __builtin_amdgcn_global_load_lds(
        (const __attribute__((address_space(1))) void*)g,
        (__attribute__((address_space(3))) void*)l, 16, 0, 0);
}

// barrier that orders LDS only — does NOT drain vmcnt
__device__ __forceinline__ void ldsbar() {
    asm volatile("s_waitcnt lgkmcnt(0)" ::: "memory");
    __builtin_amdgcn_s_barrier();
}

__device__ __forceinline__ uint32_t pk4_fp8(float a, float b, float c, float d) {
    uint32_t v = __builtin_amdgcn_cvt_pk_fp8_f32(a, b, 0, false);
    v = __builtin_amdgcn_cvt_pk_fp8_f32(c, d, v, true);
    return v;
}

// ---- kernel 1 (fused prep): X->fp8, W->Wt fp8 transpose, RoPE tables --------
__global__ __launch_bounds__(256) void prep_k(
    const float* __restrict__ X, const float* __restrict__ W,
    uint8_t* __restrict__ Xq, uint8_t* __restrict__ Wtq,
    float* __restrict__ cosT, float* __restrict__ sinT) {

    int blk = blockIdx.x;
    if (blk < 3072) {
        size_t idx = ((size_t)blk * 256 + threadIdx.x) * 8;
        float4 f0 = *(const float4*)(X + idx);
        float4 f1 = *(const float4*)(X + idx + 4);
        uint2 p;
        p.x = pk4_fp8(f0.x, f0.y, f0.z, f0.w);
        p.y = pk4_fp8(f1.x, f1.y, f1.z, f1.w);
        *(uint2*)(Xq + idx) = p;
    } else if (blk < 4224) {
        __shared__ float Ls[32][33];
        int b2 = blk - 3072;
        int n0 = (b2 % 48) * 32, k0 = (b2 / 48) * 32;
        int tx = threadIdx.x & 31, ty = threadIdx.x >> 5;
#pragma unroll
        for (int rr = 0; rr < 4; ++rr) {
            int k = ty + rr * 8;
            Ls[k][tx] = W[(size_t)(k0 + k) * NOUT + n0 + tx];
        }
        __syncthreads();
        int n = threadIdx.x >> 3, c = threadIdx.x & 7;
        uint32_t w = pk4_fp8(Ls[4*c][n], Ls[4*c+1][n], Ls[4*c+2][n], Ls[4*c+3][n]);
        *(uint32_t*)(Wtq + (size_t)(n0 + n) * HID + k0 + c * 4) = w;
    } else {
        int idx = (blk - 4224) * 256 + threadIdx.x;
        int l = idx >> 6, d = idx & 63;
        int p = d >> 1;
        float inv = powf(10000.0f, (-2.0f * (float)p) / 64.0f);
        float ang = (float)l * inv;
        cosT[idx] = cosf(ang);
        sinT[idx] = sinf(ang);
    }
}

// ---------------- kernel 2: fp8 proj GEMM + bias + RoPE -> fp8 q/k slabs -----
// (round-11 winner: double-buffered LDS + prefetch + counted vmcnt(4))
__global__ __launch_bounds__(256) void proj_rope_k(
    const uint8_t* __restrict__ Xq, const uint8_t* __restrict__ Wtq,
    const float* __restrict__ bias, const float* __restrict__ cosT,
    const float* __restrict__ sinT,
    uint8_t* __restrict__ qq, uint8_t* __restrict__ kq) {

    __shared__ __align__(16) uint8_t As[2][128 * 64];
    __shared__ __align__(16) uint8_t Bs[2][128 * 64];

    const int tid = threadIdx.x;
    const int m0 = blockIdx.x * 128, n0 = blockIdx.y * 128;
    const int lane = tid & 63, wid = tid >> 6;
    const int wm = wid >> 1, wn = wid & 1;
    const int lr = lane & 15, kg = lane >> 4;

    const int srow = tid >> 2, sc = tid & 3;

    f32x4 acc[4][4] = {};                 // [ai(n)][bi(m)]

    // prologue: stage tile 0 -> buf 0
#pragma unroll
    for (int j = 0; j < 2; ++j) {
        int r = j * 64 + srow;
        int cs = sc ^ ((r >> 1) & 3);
        gl_lds16(Wtq + (size_t)(n0 + r) * HID + cs * 16, Bs[0] + j * 4096 + tid * 16);
        gl_lds16(Xq  + (size_t)(m0 + r) * HID + cs * 16, As[0] + j * 4096 + tid * 16);
    }

    for (int it = 0; it < 12; ++it) {
        const int cur = it & 1;
        if (it < 11) {
            const int k0 = (it + 1) * 64;
            // prefetch tile it+1 into the other buffer
#pragma unroll
            for (int j = 0; j < 2; ++j) {
                int r = j * 64 + srow;
                int cs = sc ^ ((r >> 1) & 3);
                gl_lds16(Wtq + (size_t)(n0 + r) * HID + k0 + cs * 16,
                         Bs[cur ^ 1] + j * 4096 + tid * 16);
                gl_lds16(Xq  + (size_t)(m0 + r) * HID + k0 + cs * 16,
                         As[cur ^ 1] + j * 4096 + tid * 16);
            }
            // retire tile it's 4 loads; tile it+1's 4 float through
            asm volatile("s_waitcnt vmcnt(4)" ::: "memory");
        } else {
            asm volatile("s_waitcnt vmcnt(0)" ::: "memory");
        }
        __builtin_amdgcn_s_barrier();

#pragma unroll
        for (int ks = 0; ks < 2; ++ks) {
            u64 af[4], xf[4];
#pragma unroll
            for (int ai = 0; ai < 4; ++ai) {
                int row = wn * 64 + ai * 16 + lr;
                int sl = (ks * 4 + kg) ^ (row & 6);
                af[ai] = *(const u64*)(Bs[cur] + row * 64 + sl * 8);
            }
#pragma unroll
            for (int bi = 0; bi < 4; ++bi) {
                int row = wm * 64 + bi * 16 + lr;
                int sl = (ks * 4 + kg) ^ (row & 6);
                xf[bi] = *(const u64*)(As[cur] + row * 64 + sl * 8);
            }
#pragma unroll
            for (int ai = 0; ai < 4; ++ai)
#pragma unroll
                for (int bi = 0; bi < 4; ++bi)
                    acc[ai][bi] = __builtin_amdgcn_mfma_f32_16x16x32_fp8_fp8(
                        (long long)af[ai], (long long)xf[bi], acc[ai][bi], 0, 0, 0);
        }
        // all waves' ds_reads of buf[cur] done before iter it+1 overwrites it
        ldsbar();
    }

    // ---- epilogue: bias + in-lane RoPE, pack fp8, 4B stores ----
#pragma unroll
    for (int ai = 0; ai < 4; ++ai) {
        int nb = n0 + wn * 64 + ai * 16 + kg * 4;  // 4-aligned
        int h = nb >> 7, d2 = nb & 127;
        int d = d2 & 63;
        uint8_t* dst = (d2 >= 64) ? kq : qq;
        float4 b4 = *(const float4*)&bias[nb];
#pragma unroll
        for (int bi = 0; bi < 4; ++bi) {
            int m = m0 + wm * 64 + bi * 16 + lr;
            int bidx = m >> 9, lpos = m & 511;
            float4 c4 = *(const float4*)&cosT[lpos * 64 + d];
            float4 s4 = *(const float4*)&sinT[lpos * 64 + d];
            float v0 = acc[ai][bi][0] + b4.x;
            float v1 = acc[ai][bi][1] + b4.y;
            float v2 = acc[ai][bi][2] + b4.z;
            float v3 = acc[ai][bi][3] + b4.w;
            float o0 = v0 * c4.x - v1 * s4.x;
            float o1 = v1 * c4.y + v0 * s4.y;
            float o2 = v2 * c4.z - v3 * s4.z;
            float o3 = v3 * c4.w + v2 * s4.w;
            uint32_t pw = pk4_fp8(o0, o1, o2, o3);
            *(uint32_t*)(dst + (((size_t)bidx * HEADS + h) * LSEQ + lpos) * DDIM + d) = pw;
        }
    }
}

// ---------------- kernel 3: fp8 QK^T + mask/tril/scale, 128m x 512n ----------
// (round-12 best: XCD-chunked swizzle w/ bh-adjacency, Q-in-regs, single-buffer
// Ks + epilogue-overlapped prefetch, Es transpose epilogue, triangle fast-path)
__global__ __launch_bounds__(256) void attn_k(
    const uint8_t* __restrict__ qq, const uint8_t* __restrict__ kq,
    const float* __restrict__ mask, float* __restrict__ out) {

    __shared__ __align__(16) uint8_t Ks[8192];
    __shared__ __align__(16) float Es[32 * 132];
    __shared__ int wok[4];

    const int tid = threadIdx.x;
    // bijective XCD-chunked swizzle (768 = 8 XCD x 96)
    const int bid = blockIdx.x;
    const int L = (bid & 7) * 96 + (bid >> 3);
    const int bh = L >> 2;
    const int mtile = L & 3;
    const int m0 = mtile * 128;
    const int lane = tid & 63, wid = tid >> 6;
    const int wm = wid >> 1, wn = wid & 1;
    const int lr = lane & 15, kg = lane >> 4;
    const int b = bh / HEADS;

    // ---- fast-path gate: all pads over the skipped cols must be exactly 1 ----
    int myok = 1;
    for (int c0 = tid; c0 < m0; c0 += 256)
        myok &= (mask[b * LSEQ + c0] == 1.0f) ? 1 : 0;
    unsigned long long bal = __ballot(myok);
    if (lane == 0) wok[wid] = (bal == ~0ull) ? 1 : 0;
    ldsbar();
    const int nstart = (wok[0] & wok[1] & wok[2] & wok[3]) ? mtile : 0;

    const uint8_t* qbase = qq + ((size_t)bh * LSEQ + m0) * DDIM;
    const uint8_t* kbase = kq + (size_t)bh * LSEQ * DDIM;

    // stage K[nstart] (issue first so the DMA starts before the q loads)
    const int srow = tid >> 2, sc = tid & 3;
#pragma unroll
    for (int j = 0; j < 2; ++j) {
        int r = j * 64 + srow;
        int cs = sc ^ ((r >> 1) & 3);
        gl_lds16(kbase + (size_t)(nstart * 128 + r) * DDIM + cs * 16,
                 Ks + j * 4096 + tid * 16);
    }

    // Q fragments straight to registers in true k-order (swizzle self-cancels):
    // qf[ks][bi] = Q[wm*64 + bi*16 + lr][ (ks*4+kg)*8 .. +8 ]
    u64 qf[2][4];
#pragma unroll
    for (int ks = 0; ks < 2; ++ks)
#pragma unroll
        for (int bi = 0; bi < 4; ++bi)
            qf[ks][bi] = *(const u64*)(qbase + (size_t)(wm * 64 + bi * 16 + lr) * DDIM
                                       + (ks * 4 + kg) * 8);

    __syncthreads();   // full drain: K[nstart] resident (qf loads also done)

    const int colb = (tid & 31) * 4;            // 0..124
    const int rrow = tid >> 5;                  // 0..7
    float* obase = out + (size_t)bh * LSEQ * LSEQ;

    for (int nt = nstart; nt < 4; ++nt) {
        f32x4 acc[4][4] = {};                   // [ai(n)][bi(m)]
#pragma unroll
        for (int ks = 0; ks < 2; ++ks) {
            u64 af[4];
#pragma unroll
            for (int ai = 0; ai < 4; ++ai) {
                int row = wn * 64 + ai * 16 + lr;
                int sl = (ks * 4 + kg) ^ (row & 6);
                af[ai] = *(const u64*)(Ks + row * 64 + sl * 8);
            }
#pragma unroll
            for (int ai = 0; ai < 4; ++ai)
#pragma unroll
                for (int bi = 0; bi < 4; ++bi)
                    acc[ai][bi] = __builtin_amdgcn_mfma_f32_16x16x32_fp8_fp8(
                        (long long)af[ai], (long long)qf[ks][bi], acc[ai][bi], 0, 0, 0);
        }
        ldsbar();   // all waves' Ks reads complete -> safe to overwrite Ks

        const int n0 = nt * 128;
        const float4 p4 = *(const float4*)&mask[b * LSEQ + n0 + colb];

        if (nt < 3) {   // prefetch next K tile (streams under the epilogue)
#pragma unroll
            for (int j = 0; j < 2; ++j) {
                int r = j * 64 + srow;
                int cs = sc ^ ((r >> 1) & 3);
                gl_lds16(kbase + (size_t)((nt + 1) * 128 + r) * DDIM + cs * 16,
                         Ks + j * 4096 + tid * 16);
            }
        }

        // ---- epilogue: 4 rounds of 32-row LDS transpose -> coalesced stores ----
#pragma unroll
        for (int p = 0; p < 4; ++p) {
            ldsbar();   // Es free of prior-round readers
            if (wm == (p >> 1)) {
                const int bi0 = (p & 1) * 2;
#pragma unroll
                for (int bb = 0; bb < 2; ++bb) {
                    int bi = bi0 + bb;
                    int row = bb * 16 + lr;                // 0..31
#pragma unroll
                    for (int ai = 0; ai < 4; ++ai) {
                        int n = wn * 64 + ai * 16 + kg * 4;
                        *(f32x4*)&Es[row * 132 + n] = acc[ai][bi];
                    }
                }
            }
            ldsbar();   // writes visible
#pragma unroll
            for (int j = 0; j < 4; ++j) {
                int rloc = rrow + j * 8;                   // 0..31
                int m = m0 + p * 32 + rloc;
                f32x4 v = *(f32x4*)&Es[rloc * 132 + colb];
                int n = n0 + colb;
                f32x4 o;
                o[0] = (v[0] * p4.x - (1.0f - p4.x) * BIG_NEG
                        - ((m > n + 0) ? BIG_NEG : 0.0f)) * 0.125f;
                o[1] = (v[1] * p4.y - (1.0f - p4.y) * BIG_NEG
                        - ((m > n + 1) ? BIG_NEG : 0.0f)) * 0.125f;
                o[2] = (v[2] * p4.z - (1.0f - p4.z) * BIG_NEG
                        - ((m > n + 2) ? BIG_NEG : 0.0f)) * 0.125f;
                o[3] = (v[3] * p4.w - (1.0f - p4.w) * BIG_NEG
                        - ((m > n + 3) ? BIG_NEG : 0.0f)) * 0.125f;
                __builtin_nontemporal_store(o, (f32x4*)&obase[(size_t)m * LSEQ + n]);
            }
        }

        if (nt < 3) {
            // collect prefetch: 16 newest (this phase's NT stores) may float,
            // everything older (incl. the 2 gl_lds) must be done.
            asm volatile("s_waitcnt vmcnt(16) lgkmcnt(0)" ::: "memory");
            __builtin_amdgcn_s_barrier();
        }
    }

    // ---- fast-fill: constant region (pad==1, m>n for whole tile) ----
    const float CONSTV = (-BIG_NEG) * 0.125f;   // bit-exact vs ref chain
    f32x4 cv = {CONSTV, CONSTV, CONSTV, CONSTV};
    for (int nt2 = 0; nt2 < nstart; ++nt2) {
        int n = nt2 * 128 + colb;
#pragma unroll
        for (int p = 0; p < 4; ++p)
#pragma unroll
            for (int j = 0; j < 4; ++j) {
                int m = m0 + p * 32 + rrow + j * 8;
                __builtin_nontemporal_store(cv, (f32x4*)&obase[(size_t)m * LSEQ + n]);
            }
    }
}

extern "C" void kernel_launch(void* const* d_in, const int* in_sizes, int n_in,
                              void* d_out, int out_size, void* d_ws, size_t ws_size,
                              hipStream_t stream) {
    const float* X    = (const float*)d_in[0];   // (16,512,768)
    const float* mask = (const float*)d_in[1];   // (16,512)
    const float* W    = (const float*)d_in[2];   // (768,1536)
    const float* bias = (const float*)d_in[3];   // (1536,)
    float* out = (float*)d_out;                  // (16,12,512,512)

    char* ws = (char*)d_ws;
    float*   cosT = (float*)ws;                      // 131072 B
    float*   sinT = (float*)(ws + 131072);           // 131072 B
    uint8_t* Wtq  = (uint8_t*)(ws + 262144);         // 1179648 B
    uint8_t* Xq   = (uint8_t*)(ws + 1441792);        // 6291456 B
    uint8_t* qq   = (uint8_t*)(ws + 7733248);        // 6291456 B
    uint8_t* kq   = (uint8_t*)(ws + 14024704);       // 6291456 B

    prep_k<<<4352, 256, 0, stream>>>(X, W, Xq, Wtq, cosT, sinT);
    proj_rope_k<<<dim3(64, 12), 256, 0, stream>>>(Xq, Wtq, bias, cosT, sinT, qq, kq);
    attn_k<<<768, 256, 0, stream>>>(qq, kq, mask, out);
}